// Round 5
// baseline (276.239 us; speedup 1.0000x reference)
//
#include <hip/hip_runtime.h>
#include <hip/hip_bf16.h>

typedef unsigned short u16;
typedef unsigned int   u32;

#define NP     4096
#define NCH    131072
#define HBASE  393216            // rel region = 131072*3
#define CLBASE 33947648          // HBASE + 131072*256

// ws layout (bytes)
#define WS_W2F   0               // 512 frags * 1KB  (W2: frag_id = nb*16 + kc)
#define WS_W3F   524288          // 256 frags * 1KB  (W3: frag_id = nb*16 + kc)
#define WS_F1    1048576         // [4096][512] f32

using bf16x8 = __attribute__((ext_vector_type(8))) short;
using f32x4  = __attribute__((ext_vector_type(4))) float;

__device__ inline u32 pk2(float a, float b) {
  __hip_bfloat162 h = __float22bfloat162_rn(make_float2(a, b));
  return *reinterpret_cast<u32*>(&h);
}

// swizzle: 16B-slot index for (row r, bf16-col c); bijective per row
__device__ inline int swz(int r, int cg) {        // cg = col>>3
  return cg ^ (r & 7) ^ ((r >> 3) & 3);
}

// ================= K1: prep(W2,W3) + cluster + rel + f1, merged =============
// blocks [0,256): f1   [256,1280): rel   [1280,1408): W2   [1408,1472): W3
// [1472,1536): cluster
__global__ __launch_bounds__(512, 2) void k_pre(const float* __restrict__ in_feats,
                                                const float* __restrict__ Wd,
                                                const float* __restrict__ bd,
                                                const float* __restrict__ W1,
                                                const float* __restrict__ b1,
                                                const float* __restrict__ W2,
                                                const float* __restrict__ W3,
                                                u16* __restrict__ w2f,
                                                u16* __restrict__ w3f,
                                                float* __restrict__ F1,
                                                float* __restrict__ out) {
  __shared__ __align__(16) char smem[51584];
  int b = blockIdx.x, tid = threadIdx.x;

  if (b < 256) {
    // ---------------- f1: F1 = feat @ W1a + b1 (B-frags direct from W1 f32) --
    u16*   sh_a = (u16*)smem;                    // [16 r][256 k] swizzled, 8KB
    float* b1s  = (float*)(smem + 8192);         // 2KB
    int p0 = b * 16, lane = tid & 63, w = tid >> 6;
    b1s[tid] = b1[tid];
    {
      int r = tid >> 5, k0 = (tid & 31) * 8;
      const float4 v0 = *(const float4*)(in_feats + (p0 + r) * 384 + 128 + k0);
      const float4 v1 = *(const float4*)(in_feats + (p0 + r) * 384 + 128 + k0 + 4);
      uint4 o;
      o.x = pk2(v0.x, v0.y); o.y = pk2(v0.z, v0.w);
      o.z = pk2(v1.x, v1.y); o.w = pk2(v1.z, v1.w);
      int slot = (k0 >> 3) ^ (r & 7);
      *(uint4*)(sh_a + r * 256 + slot * 8) = o;
    }
    __syncthreads();
    f32x4 acc[4];
#pragma unroll
    for (int i = 0; i < 4; ++i) acc[i] = f32x4{0.f, 0.f, 0.f, 0.f};
    int col = lane & 15, q = lane >> 4, q8 = q * 8;
#pragma unroll
    for (int kc = 0; kc < 8; ++kc) {
      int slot = ((kc * 32 + q8) >> 3) ^ (col & 7);
      bf16x8 a = *(const bf16x8*)(sh_a + col * 256 + slot * 8);
#pragma unroll
      for (int nf = 0; nf < 4; ++nf) {
        const float* wp = W1 + (kc * 32 + q8) * 512 + (w * 4 + nf) * 16 + col;
        float v0 = wp[0],      v1 = wp[512],  v2 = wp[1024], v3 = wp[1536];
        float v4 = wp[2048],   v5 = wp[2560], v6 = wp[3072], v7 = wp[3584];
        union { bf16x8 v; u32 u[4]; } uu;
        uu.u[0] = pk2(v0, v1); uu.u[1] = pk2(v2, v3);
        uu.u[2] = pk2(v4, v5); uu.u[3] = pk2(v6, v7);
        acc[nf] = __builtin_amdgcn_mfma_f32_16x16x32_bf16(a, uu.v, acc[nf], 0, 0, 0);
      }
    }
    int rb = (lane >> 4) * 4;
#pragma unroll
    for (int nf = 0; nf < 4; ++nf) {
      int n = w * 64 + nf * 16 + col;
#pragma unroll
      for (int i = 0; i < 4; ++i)
        F1[(p0 + rb + i) * 512 + n] = acc[nf][i] + b1s[n];
    }
  } else if (b < 1280) {
    // ---------------- rel: relative_points, 4 parents/block -----------------
    float* wd  = (float*)smem;                   // 128x96, 48KB
    float* ne  = (float*)(smem + 49152);         // 2KB
    float* bds = (float*)(smem + 51200);         // 384B
    int p0 = (b - 256) * 4, t = tid;
#pragma unroll
    for (int i = 0; i < 6; ++i)
      *(float4*)(wd + (i * 512 + t) * 4) = *(const float4*)(Wd + (i * 512 + t) * 4);
    { int pp = t >> 7, k = t & 127; ne[t] = in_feats[(p0 + pp) * 384 + k]; }
    if (t < 96) bds[t] = bd[t];
    __syncthreads();
    if (t < 384) {
      int pp = t / 96, c = t - pp * 96;
      float acc = bds[c];
      const float* nep = ne + pp * 128;
#pragma unroll 4
      for (int k = 0; k < 128; ++k) acc += nep[k] * wd[k * 96 + c];
      out[(p0 + pp) * 96 + c] = acc;
    }
  } else if (b < 1472) {
    // ---------------- W2/W3 -> bf16 fragment layout (2 tiles/block) ---------
    float (*tile)[32][33] = (float (*)[32][33])smem;   // 8448B
    int h = tid >> 8, t = tid & 255;
    const float* src; u16* dst; int pitchN, g;
    if (b < 1408) { g = (b - 1280) * 2 + h; src = W2; dst = w2f; pitchN = 512; }
    else          { g = (b - 1408) * 2 + h; src = W3; dst = w3f; pitchN = 256; }
    int kt = g & 15, nt = g >> 4;
    {
      int kk = t >> 3, n4 = (t & 7) * 4;
      const float4 v = *(const float4*)(src + (kt * 32 + kk) * pitchN + nt * 32 + n4);
      tile[h][kk][n4 + 0] = v.x; tile[h][kk][n4 + 1] = v.y;
      tile[h][kk][n4 + 2] = v.z; tile[h][kk][n4 + 3] = v.w;
    }
    __syncthreads();
    {
      int s = t >> 1, half = t & 1, fr = s >> 6, l = s & 63;
      int n_l = fr * 16 + (l & 15);
      int k_l = (l >> 4) * 8 + half * 4;
      uint2 o;
      o.x = pk2(tile[h][k_l + 0][n_l], tile[h][k_l + 1][n_l]);
      o.y = pk2(tile[h][k_l + 2][n_l], tile[h][k_l + 3][n_l]);
      int frag_id = (nt * 2 + fr) * 16 + kt;
      *(uint2*)(dst + frag_id * 512 + l * 8 + half * 4) = o;
    }
  } else {
    // ---------------- cluster ids ------------------------------------------
    int idx = ((b - 1472) * 512 + tid) * 4;
    float c = (float)(idx >> 5);
    float* p = out + CLBASE + idx;
    __builtin_nontemporal_store(c, p + 0);
    __builtin_nontemporal_store(c, p + 1);
    __builtin_nontemporal_store(c, p + 2);
    __builtin_nontemporal_store(c, p + 3);
  }
}

// ================= K2: fused h1-build + GEMM2 + GEMM3 (M=128) ===============
__global__ __launch_bounds__(512, 2) void k_main(const float* __restrict__ W1,
                                                 const float* __restrict__ b2,
                                                 const float* __restrict__ b3,
                                                 const u16* __restrict__ w2f,
                                                 const u16* __restrict__ w3f,
                                                 const float* __restrict__ F1,
                                                 float* __restrict__ out) {
  int blk = blockIdx.x;
  int tid = threadIdx.x, lane = tid & 63, w = tid >> 6;
  __shared__ u16 sh_h[128 * 512];      // h1 then h2, swizzled 16B slots
  __shared__ float f1s[2048], w1bs[1536], b2s[512], b3s[256], rels[384];

  *(float4*)(f1s + tid * 4) = *(const float4*)(F1 + blk * 2048 + tid * 4);
  w1bs[tid]        = W1[131072 + tid];          // W1 rows 256..258
  w1bs[tid + 512]  = W1[131072 + 512 + tid];
  w1bs[tid + 1024] = W1[131072 + 1024 + tid];
  b2s[tid] = b2[tid];
  if (tid < 256) b3s[tid] = b3[tid];
  if (tid < 384) rels[tid] = out[blk * 384 + tid];
  __syncthreads();

  // ---- build h1 (128 x 512) into LDS as bf16; 16B writes, conflict-free ----
  {
    int r = tid & 31, g = tid >> 5;              // g in 0..15
#pragma unroll
    for (int rr = 0; rr < 128; rr += 32) {
      int row = rr + r, pp = rr >> 5;
      float r0 = rels[row * 3 + 0], r1 = rels[row * 3 + 1], r2 = rels[row * 3 + 2];
#pragma unroll
      for (int gg = 0; gg < 4; ++gg) {
        int c8 = g * 8 + gg * 128;
        const float4 fa = *(const float4*)(f1s + pp * 512 + c8);
        const float4 fb = *(const float4*)(f1s + pp * 512 + c8 + 4);
        const float4 wa0 = *(const float4*)(w1bs + c8);
        const float4 wb0 = *(const float4*)(w1bs + c8 + 4);
        const float4 wa1 = *(const float4*)(w1bs + 512 + c8);
        const float4 wb1 = *(const float4*)(w1bs + 512 + c8 + 4);
        const float4 wa2 = *(const float4*)(w1bs + 1024 + c8);
        const float4 wb2 = *(const float4*)(w1bs + 1024 + c8 + 4);
        float v0 = fmaxf(fa.x + r0 * wa0.x + r1 * wa1.x + r2 * wa2.x, 0.f);
        float v1 = fmaxf(fa.y + r0 * wa0.y + r1 * wa1.y + r2 * wa2.y, 0.f);
        float v2 = fmaxf(fa.z + r0 * wa0.z + r1 * wa1.z + r2 * wa2.z, 0.f);
        float v3 = fmaxf(fa.w + r0 * wa0.w + r1 * wa1.w + r2 * wa2.w, 0.f);
        float v4 = fmaxf(fb.x + r0 * wb0.x + r1 * wb1.x + r2 * wb2.x, 0.f);
        float v5 = fmaxf(fb.y + r0 * wb0.y + r1 * wb1.y + r2 * wb2.y, 0.f);
        float v6 = fmaxf(fb.z + r0 * wb0.z + r1 * wb1.z + r2 * wb2.z, 0.f);
        float v7 = fmaxf(fb.w + r0 * wb0.w + r1 * wb1.w + r2 * wb2.w, 0.f);
        uint4 o;
        o.x = pk2(v0, v1); o.y = pk2(v2, v3);
        o.z = pk2(v4, v5); o.w = pk2(v6, v7);
        *(uint4*)(sh_h + row * 512 + swz(row, c8 >> 3) * 8) = o;
      }
    }
  }
  __syncthreads();

  int col = lane & 15, q8 = (lane >> 4) * 8;

  // ---- GEMM2: h2 = relu(h1 @ W2 + b2); prefetched B-frags ----
  f32x4 acc2[8][4];
#pragma unroll
  for (int mf = 0; mf < 8; ++mf)
#pragma unroll
    for (int nf = 0; nf < 4; ++nf) acc2[mf][nf] = f32x4{0.f, 0.f, 0.f, 0.f};
  {
    const u16* w2p = w2f + (size_t)(w * 4 * 16) * 512 + lane * 8;
    bf16x8 bufA[4], bufB[4];
#pragma unroll
    for (int nf = 0; nf < 4; ++nf) bufA[nf] = *(const bf16x8*)(w2p + nf * 16 * 512);
#pragma unroll 2
    for (int kc = 0; kc < 16; ++kc) {
      const bf16x8* cur = (kc & 1) ? bufB : bufA;
      bf16x8* nxt = (kc & 1) ? bufA : bufB;
      if (kc < 15) {
#pragma unroll
        for (int nf = 0; nf < 4; ++nf)
          nxt[nf] = *(const bf16x8*)(w2p + (nf * 16 + kc + 1) * 512);
      }
      int cb = (kc * 32 + q8) >> 3;
#pragma unroll
      for (int mf = 0; mf < 8; ++mf) {
        int row = mf * 16 + col;
        bf16x8 a = *(const bf16x8*)(sh_h + row * 512 + swz(row, cb) * 8);
#pragma unroll
        for (int nf = 0; nf < 4; ++nf)
          acc2[mf][nf] = __builtin_amdgcn_mfma_f32_16x16x32_bf16(a, cur[nf], acc2[mf][nf], 0, 0, 0);
      }
    }
  }
  __syncthreads();   // all h1 reads done

  // ---- h2 -> LDS (relu + bf16, paired cvt_pk) ----
  {
    int rq = (lane >> 4) * 4;
#pragma unroll
    for (int mf = 0; mf < 8; ++mf)
#pragma unroll
      for (int nf = 0; nf < 4; ++nf) {
        int n = w * 64 + nf * 16 + col, cg = n >> 3, n7 = n & 7;
        float bv = b2s[n];
#pragma unroll
        for (int i = 0; i < 4; i += 2) {
          int r0 = mf * 16 + rq + i, r1 = r0 + 1;
          u32 p = pk2(fmaxf(acc2[mf][nf][i] + bv, 0.f),
                      fmaxf(acc2[mf][nf][i + 1] + bv, 0.f));
          sh_h[r0 * 512 + swz(r0, cg) * 8 + n7] = (u16)(p & 0xffff);
          sh_h[r1 * 512 + swz(r1, cg) * 8 + n7] = (u16)(p >> 16);
        }
      }
  }
  __syncthreads();

  // ---- GEMM3: h3 = relu(h2 @ W3 + b3); prefetched B-frags ----
  f32x4 acc3[8][2];
#pragma unroll
  for (int mf = 0; mf < 8; ++mf)
#pragma unroll
    for (int nf = 0; nf < 2; ++nf) acc3[mf][nf] = f32x4{0.f, 0.f, 0.f, 0.f};
  {
    const u16* w3p = w3f + (size_t)(w * 2 * 16) * 512 + lane * 8;
    bf16x8 bufA[2], bufB[2];
#pragma unroll
    for (int nf = 0; nf < 2; ++nf) bufA[nf] = *(const bf16x8*)(w3p + nf * 16 * 512);
#pragma unroll 2
    for (int kc = 0; kc < 16; ++kc) {
      const bf16x8* cur = (kc & 1) ? bufB : bufA;
      bf16x8* nxt = (kc & 1) ? bufA : bufB;
      if (kc < 15) {
#pragma unroll
        for (int nf = 0; nf < 2; ++nf)
          nxt[nf] = *(const bf16x8*)(w3p + (nf * 16 + kc + 1) * 512);
      }
      int cb = (kc * 32 + q8) >> 3;
#pragma unroll
      for (int mf = 0; mf < 8; ++mf) {
        int row = mf * 16 + col;
        bf16x8 a = *(const bf16x8*)(sh_h + row * 512 + swz(row, cb) * 8);
#pragma unroll
        for (int nf = 0; nf < 2; ++nf)
          acc3[mf][nf] = __builtin_amdgcn_mfma_f32_16x16x32_bf16(a, cur[nf], acc3[mf][nf], 0, 0, 0);
      }
    }
  }

  // ---- epilogue: write h (non-temporal) ----
  {
    int rq = (lane >> 4) * 4;
#pragma unroll
    for (int mf = 0; mf < 8; ++mf)
#pragma unroll
      for (int nf = 0; nf < 2; ++nf) {
        int n = w * 32 + nf * 16 + col;
        float bv = b3s[n];
#pragma unroll
        for (int i = 0; i < 4; ++i) {
          int r = mf * 16 + rq + i;
          float v = fmaxf(acc3[mf][nf][i] + bv, 0.f);
          __builtin_nontemporal_store(v, out + HBASE + (blk * 128 + r) * 256 + n);
        }
      }
  }
}

extern "C" void kernel_launch(void* const* d_in, const int* in_sizes, int n_in,
                              void* d_out, int out_size, void* d_ws, size_t ws_size,
                              hipStream_t stream) {
  const float* in_feats = (const float*)d_in[0];
  const float* Wd = (const float*)d_in[1];
  const float* bd = (const float*)d_in[2];
  const float* W1 = (const float*)d_in[3];
  const float* b1 = (const float*)d_in[4];
  const float* W2 = (const float*)d_in[5];
  const float* b2 = (const float*)d_in[6];
  const float* W3 = (const float*)d_in[7];
  const float* b3 = (const float*)d_in[8];
  float* out = (float*)d_out;
  char* ws = (char*)d_ws;
  u16*   w2f = (u16*)(ws + WS_W2F);
  u16*   w3f = (u16*)(ws + WS_W3F);
  float* F1  = (float*)(ws + WS_F1);

  k_pre<<<1536, 512, 0, stream>>>(in_feats, Wd, bd, W1, b1, W2, W3, w2f, w3f, F1, out);
  k_main<<<1024, 512, 0, stream>>>(W1, b2, b3, w2f, w3f, F1, out);
}